// Round 2
// baseline (31.099 us; speedup 1.0000x reference)
//
#include <hip/hip_runtime.h>
#include <cmath>

// NCE LM loss. N = B*T rows, D = 1024, K = 20 noise ids, V = vocab.
// Fast path: block = 256 thr (4 waves), 4 rows/block, all 20 noise rows
// staged in 80KB LDS (2 blocks/CU), hidden rows register-resident so each
// LDS noise chunk serves 4 fma-rows. Each wave: 5 noise ids x 4 rows + 1 pos dot.

#define RPB 4            // rows per block (fast path)
#define KN  20           // noise count (fast path)

__device__ __forceinline__ float log_sigmoid_f(float x) {
    // stable log(sigmoid(x)) = min(x,0) - log1p(exp(-|x|))
    return fminf(x, 0.0f) - log1pf(expf(-fabsf(x)));
}

__device__ __forceinline__ float wave_reduce(float v) {
    #pragma unroll
    for (int off = 32; off > 0; off >>= 1) v += __shfl_xor(v, off, 64);
    return v;
}

__device__ __forceinline__ float fma4(float4 a, float4 b, float acc) {
    acc = fmaf(a.x, b.x, acc);
    acc = fmaf(a.y, b.y, acc);
    acc = fmaf(a.z, b.z, acc);
    return fmaf(a.w, b.w, acc);
}

__global__ __launch_bounds__(256, 2) void nce_fast_kernel(
    const float* __restrict__ hidden,     // (N, 1024)
    const int*   __restrict__ targets,    // (N,)
    const float* __restrict__ W,          // (V, 1024)
    const int*   __restrict__ noise_ids,  // (20,)
    float* __restrict__ posp,             // (N,) per-row pos terms
    float* __restrict__ negp,             // (N,) per-wave neg sums
    float shift)
{
    __shared__ float nlds[KN * 1024];     // 80 KB: all noise rows

    const int tid  = threadIdx.x;
    const int wave = tid >> 6;
    const int lane = tid & 63;
    const int r0   = blockIdx.x * RPB;

    // ---- stage 20 noise rows into LDS (coalesced 4KB per row) ----
    for (int n = 0; n < KN; ++n) {
        const int id = noise_ids[n];
        const float4 v = *reinterpret_cast<const float4*>(W + (size_t)id * 1024 + tid * 4);
        *reinterpret_cast<float4*>(nlds + n * 1024 + tid * 4) = v;
    }

    // ---- load this block's 4 hidden rows into registers ----
    // lane owns elements {lane*4 + j*256}: instruction j is a contiguous 1KB wave load.
    float4 h[RPB][4];
    #pragma unroll
    for (int r = 0; r < RPB; ++r)
        #pragma unroll
        for (int j = 0; j < 4; ++j)
            h[r][j] = *reinterpret_cast<const float4*>(
                hidden + (size_t)(r0 + r) * 1024 + lane * 4 + j * 256);

    // ---- pos dot: wave w handles row r0+w (fresh reload avoids runtime h[wave] index; L1-hot) ----
    const int rowp = r0 + wave;
    const int tgt  = targets[rowp];
    float pacc = 0.0f;
    #pragma unroll
    for (int j = 0; j < 4; ++j) {
        const float4 b = *reinterpret_cast<const float4*>(
            W + (size_t)tgt * 1024 + lane * 4 + j * 256);
        const float4 a = *reinterpret_cast<const float4*>(
            hidden + (size_t)rowp * 1024 + lane * 4 + j * 256);
        pacc = fma4(a, b, pacc);
    }

    __syncthreads();   // LDS staging complete

    // ---- neg dots: wave w owns noise ids [w*5, w*5+5), each vs all 4 rows ----
    float acc[5][RPB];
    #pragma unroll
    for (int n = 0; n < 5; ++n)
        #pragma unroll
        for (int r = 0; r < RPB; ++r) acc[n][r] = 0.0f;

    #pragma unroll
    for (int n = 0; n < 5; ++n) {
        const int nid = wave * 5 + n;
        float4 b[4];
        #pragma unroll
        for (int j = 0; j < 4; ++j)
            b[j] = *reinterpret_cast<const float4*>(nlds + nid * 1024 + lane * 4 + j * 16 * 16);
        #pragma unroll
        for (int j = 0; j < 4; ++j)
            #pragma unroll
            for (int r = 0; r < RPB; ++r)
                acc[n][r] = fma4(b[j], h[r][j], acc[n][r]);
    }

    // ---- reductions ----
    pacc = wave_reduce(pacc);
    #pragma unroll
    for (int n = 0; n < 5; ++n)
        #pragma unroll
        for (int r = 0; r < RPB; ++r)
            acc[n][r] = wave_reduce(acc[n][r]);

    if (lane == 0) {
        posp[rowp] = log_sigmoid_f(pacc + shift);
        float nsum = 0.0f;
        #pragma unroll
        for (int n = 0; n < 5; ++n)
            #pragma unroll
            for (int r = 0; r < RPB; ++r)
                nsum += log_sigmoid_f(-(acc[n][r] + shift));
        negp[blockIdx.x * RPB + wave] = nsum;
    }
}

// ---- generic (slow) fallback for unexpected shapes: one block per row ----
__global__ __launch_bounds__(256) void nce_generic_kernel(
    const float* __restrict__ hidden, const int* __restrict__ targets,
    const float* __restrict__ W, const int* __restrict__ noise_ids,
    float* __restrict__ posp, float* __restrict__ negp,
    int D, int K, float shift)
{
    const int row  = blockIdx.x;
    const int tid  = threadIdx.x;
    const int wave = tid >> 6;
    const int lane = tid & 63;
    __shared__ float spos[4], sneg[4];

    const float* hrow = hidden + (size_t)row * D;
    const int tgt = targets[row];
    float pos = 0.0f, neg = 0.0f;
    for (int id = wave; id <= K; id += 4) {
        const int wrow = (id == 0) ? tgt : noise_ids[id - 1];
        const float* wv = W + (size_t)wrow * D;
        float acc = 0.0f;
        for (int k = lane; k < D; k += 64) acc = fmaf(hrow[k], wv[k], acc);
        acc = wave_reduce(acc);
        if (lane == 0) {
            const float s = acc + shift;
            if (id == 0) pos += log_sigmoid_f(s);
            else         neg += log_sigmoid_f(-s);
        }
    }
    if (lane == 0) { spos[wave] = pos; sneg[wave] = neg; }
    __syncthreads();
    if (tid == 0) {
        posp[row] = spos[0] + spos[1] + spos[2] + spos[3];
        negp[row] = sneg[0] + sneg[1] + sneg[2] + sneg[3];
    }
}

__global__ __launch_bounds__(256) void nce_finalize_kernel(
    const float* __restrict__ posp, const float* __restrict__ negp,
    float* __restrict__ out, int N, int K)
{
    __shared__ float sp[4], sn[4];
    const int tid  = threadIdx.x;
    const int wave = tid >> 6;
    const int lane = tid & 63;

    float p = 0.0f, n = 0.0f;
    for (int i = tid; i < N; i += 256) {
        p += posp[i];
        n += negp[i];
    }
    #pragma unroll
    for (int off = 32; off > 0; off >>= 1) {
        p += __shfl_xor(p, off, 64);
        n += __shfl_xor(n, off, 64);
    }
    if (lane == 0) { sp[wave] = p; sn[wave] = n; }
    __syncthreads();
    if (tid == 0) {
        const float P  = sp[0] + sp[1] + sp[2] + sp[3];
        const float Ng = sn[0] + sn[1] + sn[2] + sn[3];
        out[0] = -P / (float)N - Ng / ((float)N * (float)K);
    }
}

extern "C" void kernel_launch(void* const* d_in, const int* in_sizes, int n_in,
                              void* d_out, int out_size, void* d_ws, size_t ws_size,
                              hipStream_t stream) {
    const float* hidden    = (const float*)d_in[0];
    const int*   targets   = (const int*)d_in[1];
    const float* W         = (const float*)d_in[2];
    const int*   noise_ids = (const int*)d_in[3];

    const int N = in_sizes[1];             // B*T = 2048
    const int D = in_sizes[0] / N;         // 1024
    const int K = in_sizes[3];             // 20
    const int V = in_sizes[2] / D;         // 50257

    const float shift = logf((float)V) - logf((float)K);

    float* posp = (float*)d_ws;            // N floats
    float* negp = posp + N;                // N floats

    if (D == 1024 && K == KN && (N % RPB) == 0) {
        nce_fast_kernel<<<N / RPB, 256, 0, stream>>>(
            hidden, targets, W, noise_ids, posp, negp, shift);
    } else {
        nce_generic_kernel<<<N, 256, 0, stream>>>(
            hidden, targets, W, noise_ids, posp, negp, D, K, shift);
    }
    nce_finalize_kernel<<<1, 256, 0, stream>>>(posp, negp, (float*)d_out, N, K);
}